// Round 12
// baseline (5008.363 us; speedup 1.0000x reference)
//
#include <hip/hip_runtime.h>
#include <hip/hip_bf16.h>

#define B_    8192
#define D_    2048
#define H_    4096
#define C_    64
#define HALF_ 1024
#define KIN_  1088   // HALF_ + C_

typedef __attribute__((ext_vector_type(8))) short bf16x8;
typedef __attribute__((ext_vector_type(4))) float f32x4;

__device__ __forceinline__ unsigned short f2bf(float f) {
  __hip_bfloat16 h = __float2bfloat16(f);
  return *reinterpret_cast<unsigned short*>(&h);
}

__device__ __forceinline__ void gload16(const void* g, void* s) {
  __builtin_amdgcn_global_load_lds((const __attribute__((address_space(1))) void*)g,
                                   (__attribute__((address_space(3))) void*)s,
                                   16, 0, 0);
}

// W [K,N] fp32 row-major  ->  Wt [N,K] bf16 row-major (transpose + convert)
__global__ void convT(const float* __restrict__ W, unsigned short* __restrict__ Wt,
                      int K, int N) {
  __shared__ float tile[32][33];
  int tx = threadIdx.x & 31, ty = threadIdx.x >> 5;   // 32x8 threads
  int n0 = blockIdx.x * 32, k0 = blockIdx.y * 32;
#pragma unroll
  for (int i = 0; i < 4; ++i)
    tile[ty + i * 8][tx] = W[(size_t)(k0 + ty + i * 8) * N + n0 + tx];
  __syncthreads();
#pragma unroll
  for (int i = 0; i < 4; ++i)
    Wt[(size_t)(n0 + ty + i * 8) * K + k0 + tx] = f2bf(tile[tx][ty + i * 8]);
}

// A0[b, c<1024] = xsrc[b, 2c+par], A0[b, 1024:1088] = condition[b, .]  (bf16)
__global__ void build_act(const float* __restrict__ xsrc, const float* __restrict__ cond,
                          int par, unsigned short* __restrict__ A0) {
  int row = blockIdx.y;
  int col = blockIdx.x * 256 + threadIdx.x;
  if (col >= KIN_) return;
  float v;
  if (col < HALF_) {
    float2 p = ((const float2*)xsrc)[(size_t)row * (D_ / 2) + col];
    v = par ? p.y : p.x;
  } else {
    v = cond[(size_t)row * C_ + (col - HALF_)];
  }
  A0[(size_t)row * KIN_ + col] = f2bf(v);
}

// ---------------------------------------------------------------------------
// R12: 256x256 tile, 16 waves (4Mx4N of 64x64), BK=32. A staged via LDS
// (3-buffer 48 KiB ring, R4-verified swizzle, 0 conflicts); B-frags loaded
// DIRECTLY global->VGPR (register double-buffer, static ping-pong).
// Rationale (R11 counters): with both operands in LDS, LDS traffic/window =
// 160 KB >= 1250 cyc > MFMA 1032 cyc -> LDS-BW-bound at 56% MfmaUtil. B's
// per-window working set is 16 KB/CU (L1-resident; 4 same-wc waves share
// lines), so direct gathers offload 80 KB/window from LDS -> LDS (80 KB ~
// 625-940 cyc) < MFMA -> MFMA-bound.
//
// vmcnt ledger (B loads now occupy the queue):
//   window T issues: [LOADB bv(T+1):4, STAGE A(T+2):2]; queue at MFMA(T):
//   B(T):4, A(T+1):2, B(T+1):4, A(T+2):2. Compiler auto-drains B(T) before
//   MFMA(T) (register dependency). End-of-window manual vmcnt(6) drains
//   A(T+1) (LDS visibility, invisible to compiler) leaving B(T+1)+A(T+2).
//   Tail NT-2: no stage -> vmcnt(4). Tail NT-1: compute only (auto vmcnt(0)
//   before its MFMA). Prologue: stage A(0),A(1), LOADB bv0(0), vmcnt(0).
//   NT = K/32 is even for all K here (34, 128, 128).
// Overwrite-safety: stage target buf holds A(T-1), whose ds_reads fed
// MFMA(T-1) (compiler lgkm wait) before the barrier ending window T-1. SAFE.
// MODE 0: C = bf16(relu(.+bias)) via per-wave LDS bounce. MODE 1: fused
// coupling epilogue.
// ---------------------------------------------------------------------------
template <int MODE>
__global__ __launch_bounds__(1024, 4)
void gemmk(const unsigned short* __restrict__ A,
           const unsigned short* __restrict__ Bt,
           const float* __restrict__ bias,
           unsigned short* __restrict__ Cout,
           const float* __restrict__ xold, float* __restrict__ xnew,
           float* __restrict__ part, int par,
           int M, int N, int K) {
  __shared__ unsigned short lds[65536];   // 128 KiB (A-ring 48 KiB + epilogue)
  char* ldsb = (char*)lds;
  const int tid = threadIdx.x;
  const int w = tid >> 6, lane = tid & 63;
  const int fr = lane & 15, fq = lane >> 4;
  const int wr = w >> 2, wc = w & 3;          // 4M x 4N waves, wave tile 64x64

  // XCD-aware block swizzle (nwg % 8 == 0 for all our grids)
  const int nbx = N >> 8;
  const int nwg = (int)gridDim.x;
  const int cpx = nwg >> 3;
  const int bid = (int)blockIdx.x;
  const int swz = (bid & 7) * cpx + (bid >> 3);
  const int by = swz / nbx, bx = swz - by * nbx;
  const int m0 = by << 8, n0 = bx << 8;

  // read-side swizzled A base offset within a buffer (R4-verified pattern)
  const int chunkp = (((fr & 1) << 2) | fq) ^ (fr >> 1);
  const int A0 = (wr * 32 + (fr >> 1)) * 128 + chunkp * 16;

  // stage-side: inverse-swizzled per-lane global source; linear LDS dest.
  // 1024 threads x 16B = one full 16KB A-slab per gload16 call.
  const int p = tid >> 3, cph = tid & 7;
  const int clg = cph ^ (p & 7);
  const int rowS = 2 * p + (clg >> 2);
  const int kcolS = (clg & 3) * 8;
  const unsigned short* sA0 = A + (size_t)(m0 + rowS) * K + kcolS;
  const int dst0 = tid * 16;

  // B-frag gather pointers: lane reads Bt[n0 + wc*64 + n*16 + fr][k..k+8]
  const unsigned short* pB0 = Bt + (size_t)(n0 + wc * 64 + fr) * K + fq * 8;
  const unsigned short* pB1 = pB0 + (size_t)16 * K;
  const unsigned short* pB2 = pB0 + (size_t)32 * K;
  const unsigned short* pB3 = pB0 + (size_t)48 * K;

#define STAGE_A(OFF) do {                                                    \
    gload16(sA0, ldsb + (OFF) + dst0);                                       \
    sA0 += 32;                                                               \
  } while (0)

#define LOADB(BV) do {                                                       \
    BV[0] = *(const bf16x8*)pB0; pB0 += 32;                                  \
    BV[1] = *(const bf16x8*)pB1; pB1 += 32;                                  \
    BV[2] = *(const bf16x8*)pB2; pB2 += 32;                                  \
    BV[3] = *(const bf16x8*)pB3; pB3 += 32;                                  \
  } while (0)

// window: [ds_read A(T) from cur; LOADB bv(T+1); stage A(T+2); MFMA(T) on
// BVC; vmcnt(VM); barrier; rotate ring]
#define WIN(BVC, BVL, LB, STG, VM)                                           \
  {                                                                          \
    bf16x8 av[4];                                                            \
    _Pragma("unroll") for (int m = 0; m < 4; ++m)                            \
      av[m] = *(const bf16x8*)(ldsb + cur + A0 + m * 1024);                  \
    if (LB) LOADB(BVL);                                                      \
    if (STG) STAGE_A(stg);                                                   \
    __builtin_amdgcn_s_setprio(1);                                           \
    _Pragma("unroll") for (int m = 0; m < 4; ++m)                            \
      _Pragma("unroll") for (int n = 0; n < 4; ++n)                          \
        acc[m][n] = __builtin_amdgcn_mfma_f32_16x16x32_bf16(                 \
            av[m], BVC[n], acc[m][n], 0, 0, 0);                              \
    __builtin_amdgcn_s_setprio(0);                                           \
    if (VM == 1) asm volatile("s_waitcnt vmcnt(6)" ::: "memory");            \
    if (VM == 2) asm volatile("s_waitcnt vmcnt(4)" ::: "memory");            \
    __builtin_amdgcn_sched_barrier(0);                                       \
    __builtin_amdgcn_s_barrier();                                            \
    cur = (cur == 32768) ? 0 : cur + 16384;                                  \
    stg = (stg == 32768) ? 0 : stg + 16384;                                  \
  }

  f32x4 acc[4][4];
  f32x4 z4 = {0.f, 0.f, 0.f, 0.f};
#pragma unroll
  for (int m = 0; m < 4; ++m)
#pragma unroll
    for (int n = 0; n < 4; ++n) acc[m][n] = z4;

  const int NT = K >> 5;   // BK=32; NT even (34 / 128 / 64)

  bf16x8 bv0[4], bv1[4];

  // prologue: stage A(0)->buf0, A(1)->buf1; load bv0 = B(0); drain all
  STAGE_A(0);
  STAGE_A(16384);
  LOADB(bv0);
  asm volatile("s_waitcnt vmcnt(0)" ::: "memory");
  __builtin_amdgcn_sched_barrier(0);
  __builtin_amdgcn_s_barrier();
  int cur = 0, stg = 32768;

  for (int T = 0; T < NT - 2; T += 2) {
    WIN(bv0, bv1, 1, 1, 1)   // even: compute B(T),  load B(T+1)
    WIN(bv1, bv0, 1, 1, 1)   // odd:  compute B(T+1), load B(T+2)
  }
  WIN(bv0, bv1, 1, 0, 2)     // T = NT-2: load B(NT-1), no stage, vmcnt(4)
  WIN(bv1, bv0, 0, 0, 0)     // T = NT-1: compute only
#undef WIN
#undef LOADB
#undef STAGE_A

  // ---- epilogue ---- (C/D frag layout: row = fq*4 + r, col = fr; m89/m91)
  if (MODE == 0) {
    // bf16 + relu via per-wave LDS bounce: wave region w*8192 = [64][128B],
    // chunk ^= fq swizzle (<=2-way = free, R4-verified pattern).
    __builtin_amdgcn_s_barrier();   // all waves done reading ring buffers
#pragma unroll
    for (int m = 0; m < 4; ++m)
#pragma unroll
      for (int n = 0; n < 4; ++n) {
        int gcol = n0 + wc * 64 + n * 16 + fr;
        float bb = bias[gcol];
#pragma unroll
        for (int r = 0; r < 4; ++r) {
          float v = fmaxf(acc[m][n][r] + bb, 0.f);
          int lrow = m * 16 + fq * 4 + r;
          *(unsigned short*)(ldsb + w * 8192 + lrow * 128 + ((n ^ fq) * 32) + fr * 2) = f2bf(v);
        }
      }
    asm volatile("s_waitcnt lgkmcnt(0)" ::: "memory");   // own-wave region only
    __builtin_amdgcn_sched_barrier(0);
    unsigned short* Cb = Cout + (size_t)(m0 + wr * 64) * N + n0 + wc * 64;
    const int sub = lane & 7;
#pragma unroll
    for (int i = 0; i < 8; ++i) {
      int lrow = i * 8 + (lane >> 3);
      int phys = (sub >> 1) ^ ((lrow >> 2) & 3);
      bf16x8 val = *(const bf16x8*)(ldsb + w * 8192 + lrow * 128 + phys * 32 + (sub & 1) * 16);
      *(bf16x8*)(Cb + (size_t)lrow * N + sub * 8) = val;
    }
  } else {
    // fused coupling: even col 2j = S, odd = T (pair via shfl_xor 1);
    // xnew[row][2j+par] = xold[row][2j+par]*exp(S)+T; S partials -> part.
#pragma unroll
    for (int m = 0; m < 4; ++m) {
      float srow[4] = {0.f, 0.f, 0.f, 0.f};
#pragma unroll
      for (int n = 0; n < 4; ++n) {
        int gcol = n0 + wc * 64 + n * 16 + fr;
        float bb = bias[gcol];
#pragma unroll
        for (int r = 0; r < 4; ++r) {
          float v = acc[m][n][r] + bb;
          float vp = __shfl_xor(v, 1);
          if (!(fr & 1)) {
            int grow = m0 + wr * 64 + m * 16 + fq * 4 + r;
            size_t idx = (size_t)grow * N + gcol + par;
            xnew[idx] = xold[idx] * expf(v) + vp;
            srow[r] += v;
          }
        }
      }
#pragma unroll
      for (int r = 0; r < 4; ++r) {
        float s = srow[r];
        s += __shfl_xor(s, 2);
        s += __shfl_xor(s, 4);
        s += __shfl_xor(s, 8);
        if (fr == 0) {
          int grow = m0 + wr * 64 + m * 16 + fq * 4 + r;
          part[(size_t)grow * 32 + bx * 4 + wc] = s;
        }
      }
    }
  }
}

// logdet[row] (= or +=) sum of 32 column-group partials
__global__ void reduce_logdet(const float* __restrict__ P, float* __restrict__ logdet, int add) {
  int row = blockIdx.x * 256 + threadIdx.x;
  float s = 0.f;
#pragma unroll
  for (int g = 0; g < 32; ++g) s += P[(size_t)row * 32 + g];
  logdet[row] = add ? (logdet[row] + s) : s;
}

extern "C" void kernel_launch(void* const* d_in, const int* in_sizes, int n_in,
                              void* d_out, int out_size, void* d_ws, size_t ws_size,
                              hipStream_t stream) {
  const float* z    = (const float*)d_in[0];
  const float* cond = (const float*)d_in[1];
  const float* W1   = (const float*)d_in[4];
  const float* b1   = (const float*)d_in[5];
  const float* W2   = (const float*)d_in[6];
  const float* b2   = (const float*)d_in[7];
  const float* W3   = (const float*)d_in[8];
  const float* b3   = (const float*)d_in[9];

  float* xout   = (float*)d_out;                 // [B, D]
  float* logdet = xout + (size_t)B_ * D_;        // [B]

  // workspace (160 MiB): Wt 32 MiB | H1 64 MiB (h1 / logdet partials) |
  //                      H2 64 MiB (A0 input acts / h2)
  char* ws = (char*)d_ws;
  unsigned short* Wt = (unsigned short*)ws;
  unsigned short* H1 = (unsigned short*)(ws + 33554432);
  unsigned short* H2 = (unsigned short*)(ws + 33554432 + 67108864);
  float* Pp = (float*)H1;          // [B][32] S-partials (H1 free during GEMM3)
  unsigned short* A0 = H2;

  for (int blk = 0; blk < 2; ++blk) {
    const float* W1b = W1 + (size_t)blk * KIN_ * H_;
    const float* W2b = W2 + (size_t)blk * H_ * H_;
    const float* W3b = W3 + (size_t)blk * H_ * D_;
    const float* b1b = b1 + (size_t)blk * H_;
    const float* b2b = b2 + (size_t)blk * H_;
    const float* b3b = b3 + (size_t)blk * D_;
    // identity channels parity 1-blk; transformed channels parity blk.
    const float* xsrc = blk ? xout : z;

    // GEMM1: [B,1088] x [1088,4096]
    convT<<<dim3(H_ / 32, KIN_ / 32), 256, 0, stream>>>(W1b, Wt, KIN_, H_);
    build_act<<<dim3(5, B_), 256, 0, stream>>>(xsrc, cond, 1 - blk, A0);
    gemmk<0><<<dim3((B_ / 256) * (H_ / 256)), 1024, 0, stream>>>(
        A0, Wt, b1b, H1, nullptr, nullptr, nullptr, 0, B_, H_, KIN_);

    // GEMM2: [B,4096] x [4096,4096]
    convT<<<dim3(H_ / 32, H_ / 32), 256, 0, stream>>>(W2b, Wt, H_, H_);
    gemmk<0><<<dim3((B_ / 256) * (H_ / 256)), 1024, 0, stream>>>(
        H1, Wt, b2b, H2, nullptr, nullptr, nullptr, 0, B_, H_, H_);

    // GEMM3: [B,4096] x [4096,2048] with fused coupling epilogue
    convT<<<dim3(D_ / 32, H_ / 32), 256, 0, stream>>>(W3b, Wt, H_, D_);
    gemmk<1><<<dim3((B_ / 256) * (D_ / 256)), 1024, 0, stream>>>(
        H2, Wt, b3b, nullptr, z, xout, Pp, blk, B_, D_, H_);

    reduce_logdet<<<dim3(B_ / 256), 256, 0, stream>>>(Pp, logdet, blk);
  }
}

// Round 13
// 1318.273 us; speedup vs baseline: 3.7992x; 3.7992x over previous
//
#include <hip/hip_runtime.h>
#include <hip/hip_bf16.h>

#define B_    8192
#define D_    2048
#define H_    4096
#define C_    64
#define HALF_ 1024
#define KIN_  1088   // HALF_ + C_

typedef __attribute__((ext_vector_type(8))) short bf16x8;
typedef __attribute__((ext_vector_type(4))) float f32x4;

__device__ __forceinline__ unsigned short f2bf(float f) {
  __hip_bfloat16 h = __float2bfloat16(f);
  return *reinterpret_cast<unsigned short*>(&h);
}

__device__ __forceinline__ void gload16(const void* g, void* s) {
  __builtin_amdgcn_global_load_lds((const __attribute__((address_space(1))) void*)g,
                                   (__attribute__((address_space(3))) void*)s,
                                   16, 0, 0);
}

// W [K,N] fp32 row-major -> Bp packed bf16 in MFMA B-frag order:
// frag (cn = col/16, ck = k/32), lane (fq=l>>4, fr=l&15) holds
// Bt[cn*16+fr][ck*32 + fq*8 .. +8] at Bp[((cn*(K/32)+ck)*64 + l)*8].
// A wave's frag load = contiguous 1KB dwordx4 (fully coalesced).
__global__ void convT_pack(const float* __restrict__ W, unsigned short* __restrict__ Bp,
                           int K, int N) {
  __shared__ float tile[32][33];
  int tx = threadIdx.x & 31, ty = threadIdx.x >> 5;   // 32x8 threads
  int n0 = blockIdx.x * 32, k0 = blockIdx.y * 32;
#pragma unroll
  for (int i = 0; i < 4; ++i)
    tile[ty + i * 8][tx] = W[(size_t)(k0 + ty + i * 8) * N + n0 + tx];
  __syncthreads();
  int lane = threadIdx.x & 63;
  int fr = lane & 15, fq = lane >> 4;
  int cl = (threadIdx.x >> 6) & 1;    // cn_local (0..1)
  int eh = threadIdx.x >> 7;          // elem half (0..1)
  int cn = (n0 >> 4) + cl, ck = k0 >> 5;
  unsigned short out[4];
#pragma unroll
  for (int e2 = 0; e2 < 4; ++e2)
    out[e2] = f2bf(tile[fq * 8 + eh * 4 + e2][cl * 16 + fr]);
  size_t base = ((size_t)(cn * (K >> 5) + ck) * 64 + lane) * 8 + eh * 4;
  *(ushort4*)(Bp + base) = *(ushort4*)out;
}

// A0[b, c<1024] = xsrc[b, 2c+par], A0[b, 1024:1088] = condition[b, .]  (bf16)
__global__ void build_act(const float* __restrict__ xsrc, const float* __restrict__ cond,
                          int par, unsigned short* __restrict__ A0) {
  int row = blockIdx.y;
  int col = blockIdx.x * 256 + threadIdx.x;
  if (col >= KIN_) return;
  float v;
  if (col < HALF_) {
    float2 p = ((const float2*)xsrc)[(size_t)row * (D_ / 2) + col];
    v = par ? p.y : p.x;
  } else {
    v = cond[(size_t)row * C_ + (col - HALF_)];
  }
  A0[(size_t)row * KIN_ + col] = f2bf(v);
}

// ---------------------------------------------------------------------------
// R13: 256x256 tile, 16 waves (4Mx4N of 64x64), BK=32. A via LDS 3-buffer
// 48 KiB ring (R4-verified swizzle, 0 conflicts); B via SINGLE-BUFFERED
// window-local coalesced frag loads from packed Bp (1KB dwordx4 per frag,
// L1/L2-resident: 4 same-wc waves share lines; unique 16KB/CU/window).
// Registers: acc 64 + av 16 + bv 16 (transient) + addr ~16 -> fits 128
// (R12's cross-window bv double-buffer spilled; this cannot).
//
// LDS traffic/window: A reads 64KB + A stage 16KB = 80KB ~ 940 cyc < MFMA
// 1032 cyc -> MFMA-bound.
//
// FIFO ledger (window T): entering queue [A(T+1)]. Issue B(T)x4, A(T+2)x1
// -> [A(T+1), B0..3, A(T+2)]. Compiler's pre-MFMA wait on bv[0] = vmcnt(4)
// drains A(T+1)+B0 (FIFO) -> end-of-window barrier publishes A(T+1) for the
// next window's ds_reads. Stage target buf holds A(T-1), read-complete
// before the previous barrier (3-ring). Tails (T=NT-2, NT-1): no stage,
// vmcnt(0) safety. Prologue: stage A(0),A(1); vmcnt(1); barrier.
// MODE 0: C = bf16(relu(.+bias)) via per-wave LDS bounce. MODE 1: fused
// coupling epilogue.
// ---------------------------------------------------------------------------
template <int MODE>
__global__ __launch_bounds__(1024, 4)
void gemmk(const unsigned short* __restrict__ A,
           const unsigned short* __restrict__ Bp,
           const float* __restrict__ bias,
           unsigned short* __restrict__ Cout,
           const float* __restrict__ xold, float* __restrict__ xnew,
           float* __restrict__ part, int par,
           int M, int N, int K) {
  __shared__ unsigned short lds[65536];   // 128 KiB (A-ring 48 KiB + epilogue)
  char* ldsb = (char*)lds;
  const int tid = threadIdx.x;
  const int w = tid >> 6, lane = tid & 63;
  const int fr = lane & 15, fq = lane >> 4;
  const int wr = w >> 2, wc = w & 3;          // 4M x 4N waves, wave tile 64x64

  // XCD-aware block swizzle (nwg % 8 == 0 for all our grids)
  const int nbx = N >> 8;
  const int nwg = (int)gridDim.x;
  const int cpx = nwg >> 3;
  const int bid = (int)blockIdx.x;
  const int swz = (bid & 7) * cpx + (bid >> 3);
  const int by = swz / nbx, bx = swz - by * nbx;
  const int m0 = by << 8, n0 = bx << 8;

  // read-side swizzled A base offset within a buffer (R4-verified pattern)
  const int chunkp = (((fr & 1) << 2) | fq) ^ (fr >> 1);
  const int A0 = (wr * 32 + (fr >> 1)) * 128 + chunkp * 16;

  // stage-side: inverse-swizzled per-lane global source; linear LDS dest.
  // 1024 threads x 16B = one full 16KB A-slab per gload16 call.
  const int p = tid >> 3, cph = tid & 7;
  const int clg = cph ^ (p & 7);
  const int rowS = 2 * p + (clg >> 2);
  const int kcolS = (clg & 3) * 8;
  const unsigned short* sA0 = A + (size_t)(m0 + rowS) * K + kcolS;
  const int dst0 = tid * 16;

  // packed-B frag pointers: frag n of wave wc at window T is at
  // ((cn0+n)*NTK + T)*512 elems; advance 512 elems (1KB) per window.
  const int NTK = K >> 5;
  const int cn0 = (n0 >> 4) + wc * 4;
  const unsigned short* pB0 = Bp + ((size_t)(cn0 + 0) * NTK * 64 + lane) * 8;
  const unsigned short* pB1 = Bp + ((size_t)(cn0 + 1) * NTK * 64 + lane) * 8;
  const unsigned short* pB2 = Bp + ((size_t)(cn0 + 2) * NTK * 64 + lane) * 8;
  const unsigned short* pB3 = Bp + ((size_t)(cn0 + 3) * NTK * 64 + lane) * 8;

#define STAGE_A(OFF) do {                                                    \
    gload16(sA0, ldsb + (OFF) + dst0);                                       \
    sA0 += 32;                                                               \
  } while (0)

#define WIN(STG, VM)                                                         \
  {                                                                          \
    bf16x8 av[4], bv[4];                                                     \
    bv[0] = *(const bf16x8*)pB0; pB0 += 512;                                 \
    bv[1] = *(const bf16x8*)pB1; pB1 += 512;                                 \
    bv[2] = *(const bf16x8*)pB2; pB2 += 512;                                 \
    bv[3] = *(const bf16x8*)pB3; pB3 += 512;                                 \
    _Pragma("unroll") for (int m = 0; m < 4; ++m)                            \
      av[m] = *(const bf16x8*)(ldsb + cur + A0 + m * 1024);                  \
    if (STG) STAGE_A(stg);                                                   \
    __builtin_amdgcn_sched_barrier(0);                                       \
    __builtin_amdgcn_s_setprio(1);                                           \
    _Pragma("unroll") for (int m = 0; m < 4; ++m)                            \
      _Pragma("unroll") for (int n = 0; n < 4; ++n)                          \
        acc[m][n] = __builtin_amdgcn_mfma_f32_16x16x32_bf16(                 \
            av[m], bv[n], acc[m][n], 0, 0, 0);                               \
    __builtin_amdgcn_s_setprio(0);                                           \
    __builtin_amdgcn_sched_barrier(0);                                       \
    if (VM == 1) asm volatile("s_waitcnt vmcnt(1)" ::: "memory");            \
    if (VM == 2) asm volatile("s_waitcnt vmcnt(0)" ::: "memory");            \
    __builtin_amdgcn_sched_barrier(0);                                       \
    __builtin_amdgcn_s_barrier();                                            \
    cur = (cur == 32768) ? 0 : cur + 16384;                                  \
    stg = (stg == 32768) ? 0 : stg + 16384;                                  \
  }

  f32x4 acc[4][4];
  f32x4 z4 = {0.f, 0.f, 0.f, 0.f};
#pragma unroll
  for (int m = 0; m < 4; ++m)
#pragma unroll
    for (int n = 0; n < 4; ++n) acc[m][n] = z4;

  const int NT = K >> 5;   // BK=32; NT >= 4 for all our K

  // prologue: stage A(0)->buf0, A(1)->buf1; confirm A(0); publish
  STAGE_A(0);
  STAGE_A(16384);
  asm volatile("s_waitcnt vmcnt(1)" ::: "memory");
  __builtin_amdgcn_sched_barrier(0);
  __builtin_amdgcn_s_barrier();
  int cur = 0, stg = 32768;

  for (int T = 0; T < NT - 2; ++T) {
    WIN(1, 1)
  }
  WIN(0, 2)   // T = NT-2
  WIN(0, 0)   // T = NT-1
#undef WIN
#undef STAGE_A

  // ---- epilogue ---- (C/D frag layout: row = fq*4 + r, col = fr; m89/m91)
  if (MODE == 0) {
    // bf16 + relu via per-wave LDS bounce: wave region w*8192 = [64][128B],
    // chunk ^= fq swizzle (<=2-way = free, R4-verified pattern).
    __builtin_amdgcn_s_barrier();   // all waves done reading ring buffers
#pragma unroll
    for (int m = 0; m < 4; ++m)
#pragma unroll
      for (int n = 0; n < 4; ++n) {
        int gcol = n0 + wc * 64 + n * 16 + fr;
        float bb = bias[gcol];
#pragma unroll
        for (int r = 0; r < 4; ++r) {
          float v = fmaxf(acc[m][n][r] + bb, 0.f);
          int lrow = m * 16 + fq * 4 + r;
          *(unsigned short*)(ldsb + w * 8192 + lrow * 128 + ((n ^ fq) * 32) + fr * 2) = f2bf(v);
        }
      }
    asm volatile("s_waitcnt lgkmcnt(0)" ::: "memory");   // own-wave region only
    __builtin_amdgcn_sched_barrier(0);
    unsigned short* Cb = Cout + (size_t)(m0 + wr * 64) * N + n0 + wc * 64;
    const int sub = lane & 7;
#pragma unroll
    for (int i = 0; i < 8; ++i) {
      int lrow = i * 8 + (lane >> 3);
      int phys = (sub >> 1) ^ ((lrow >> 2) & 3);
      bf16x8 val = *(const bf16x8*)(ldsb + w * 8192 + lrow * 128 + phys * 32 + (sub & 1) * 16);
      *(bf16x8*)(Cb + (size_t)lrow * N + sub * 8) = val;
    }
  } else {
    // fused coupling: even col 2j = S, odd = T (pair via shfl_xor 1);
    // xnew[row][2j+par] = xold[row][2j+par]*exp(S)+T; S partials -> part.
#pragma unroll
    for (int m = 0; m < 4; ++m) {
      float srow[4] = {0.f, 0.f, 0.f, 0.f};
#pragma unroll
      for (int n = 0; n < 4; ++n) {
        int gcol = n0 + wc * 64 + n * 16 + fr;
        float bb = bias[gcol];
#pragma unroll
        for (int r = 0; r < 4; ++r) {
          float v = acc[m][n][r] + bb;
          float vp = __shfl_xor(v, 1);
          if (!(fr & 1)) {
            int grow = m0 + wr * 64 + m * 16 + fq * 4 + r;
            size_t idx = (size_t)grow * N + gcol + par;
            xnew[idx] = xold[idx] * expf(v) + vp;
            srow[r] += v;
          }
        }
      }
#pragma unroll
      for (int r = 0; r < 4; ++r) {
        float s = srow[r];
        s += __shfl_xor(s, 2);
        s += __shfl_xor(s, 4);
        s += __shfl_xor(s, 8);
        if (fr == 0) {
          int grow = m0 + wr * 64 + m * 16 + fq * 4 + r;
          part[(size_t)grow * 32 + bx * 4 + wc] = s;
        }
      }
    }
  }
}

// logdet[row] (= or +=) sum of 32 column-group partials
__global__ void reduce_logdet(const float* __restrict__ P, float* __restrict__ logdet, int add) {
  int row = blockIdx.x * 256 + threadIdx.x;
  float s = 0.f;
#pragma unroll
  for (int g = 0; g < 32; ++g) s += P[(size_t)row * 32 + g];
  logdet[row] = add ? (logdet[row] + s) : s;
}

extern "C" void kernel_launch(void* const* d_in, const int* in_sizes, int n_in,
                              void* d_out, int out_size, void* d_ws, size_t ws_size,
                              hipStream_t stream) {
  const float* z    = (const float*)d_in[0];
  const float* cond = (const float*)d_in[1];
  const float* W1   = (const float*)d_in[4];
  const float* b1   = (const float*)d_in[5];
  const float* W2   = (const float*)d_in[6];
  const float* b2   = (const float*)d_in[7];
  const float* W3   = (const float*)d_in[8];
  const float* b3   = (const float*)d_in[9];

  float* xout   = (float*)d_out;                 // [B, D]
  float* logdet = xout + (size_t)B_ * D_;        // [B]

  // workspace (160 MiB): Bp 32 MiB (packed weights) | H1 64 MiB (h1 / logdet
  //                      partials) | H2 64 MiB (A0 input acts / h2)
  char* ws = (char*)d_ws;
  unsigned short* Wt = (unsigned short*)ws;
  unsigned short* H1 = (unsigned short*)(ws + 33554432);
  unsigned short* H2 = (unsigned short*)(ws + 33554432 + 67108864);
  float* Pp = (float*)H1;          // [B][32] S-partials (H1 free during GEMM3)
  unsigned short* A0 = H2;

  for (int blk = 0; blk < 2; ++blk) {
    const float* W1b = W1 + (size_t)blk * KIN_ * H_;
    const float* W2b = W2 + (size_t)blk * H_ * H_;
    const float* W3b = W3 + (size_t)blk * H_ * D_;
    const float* b1b = b1 + (size_t)blk * H_;
    const float* b2b = b2 + (size_t)blk * H_;
    const float* b3b = b3 + (size_t)blk * D_;
    // identity channels parity 1-blk; transformed channels parity blk.
    const float* xsrc = blk ? xout : z;

    // GEMM1: [B,1088] x [1088,4096]
    convT_pack<<<dim3(H_ / 32, KIN_ / 32), 256, 0, stream>>>(W1b, Wt, KIN_, H_);
    build_act<<<dim3(5, B_), 256, 0, stream>>>(xsrc, cond, 1 - blk, A0);
    gemmk<0><<<dim3((B_ / 256) * (H_ / 256)), 1024, 0, stream>>>(
        A0, Wt, b1b, H1, nullptr, nullptr, nullptr, 0, B_, H_, KIN_);

    // GEMM2: [B,4096] x [4096,4096]
    convT_pack<<<dim3(H_ / 32, H_ / 32), 256, 0, stream>>>(W2b, Wt, H_, H_);
    gemmk<0><<<dim3((B_ / 256) * (H_ / 256)), 1024, 0, stream>>>(
        H1, Wt, b2b, H2, nullptr, nullptr, nullptr, 0, B_, H_, H_);

    // GEMM3: [B,4096] x [4096,2048] with fused coupling epilogue
    convT_pack<<<dim3(D_ / 32, H_ / 32), 256, 0, stream>>>(W3b, Wt, H_, D_);
    gemmk<1><<<dim3((B_ / 256) * (D_ / 256)), 1024, 0, stream>>>(
        H2, Wt, b3b, nullptr, z, xout, Pp, blk, B_, D_, H_);

    reduce_logdet<<<dim3(B_ / 256), 256, 0, stream>>>(Pp, logdet, blk);
  }
}